// Round 1
// baseline (1345.751 us; speedup 1.0000x reference)
//
#include <hip/hip_runtime.h>
#include <hip/hip_bf16.h>
#include <math.h>

// Problem constants
#define D_MODEL 768
#define D_STATE 16
#define D_CONV  4
#define D_INNER 1536
#define BATCH   2
#define SEQ     2048
#define MROWS   (BATCH * SEQ)        // 4096
#define NXZ     (2 * D_INNER)        // 3072
#define NSSM    (2 * D_STATE + 1)    // 33

// ---------------------------------------------------------------------------
// GEMM: C[M,N] = A[M,K] @ W[N,K]^T + bias[N]   (both A and W are K-contiguous)
// 128x128 tile, BK=8, 256 threads, 8x8 per thread. M,N,K all divide evenly.
// ---------------------------------------------------------------------------
#define BM 128
#define BN 128
#define BK 8
#define TM 8
#define TN 8

__global__ __launch_bounds__(256) void gemm_tn(
    const float* __restrict__ A, const float* __restrict__ W,
    const float* __restrict__ bias, float* __restrict__ C,
    int M, int N, int K)
{
    __shared__ float As[BK][BM];
    __shared__ float Ws[BK][BN];

    const int bm = blockIdx.y * BM;
    const int bn = blockIdx.x * BN;
    const int tid = threadIdx.x;

    // Loader mapping: 256 threads, each one float4 from A tile and W tile
    const int lrow = tid >> 1;          // 0..127
    const int lcol = (tid & 1) * 4;     // 0 or 4

    // Compute mapping: 16x16 threads, each TMxTN
    const int tr = (tid >> 4) * TM;     // 0..120
    const int tc = (tid & 15) * TN;     // 0..120

    const float* Aptr = A + (size_t)(bm + lrow) * K + lcol;
    const float* Wptr = W + (size_t)(bn + lrow) * K + lcol;

    float acc[TM][TN];
#pragma unroll
    for (int i = 0; i < TM; ++i)
#pragma unroll
        for (int j = 0; j < TN; ++j) acc[i][j] = 0.f;

    for (int k0 = 0; k0 < K; k0 += BK) {
        float4 av = *(const float4*)(Aptr + k0);
        float4 wv = *(const float4*)(Wptr + k0);
        __syncthreads();   // previous iteration's LDS reads complete
        As[lcol + 0][lrow] = av.x;
        As[lcol + 1][lrow] = av.y;
        As[lcol + 2][lrow] = av.z;
        As[lcol + 3][lrow] = av.w;
        Ws[lcol + 0][lrow] = wv.x;
        Ws[lcol + 1][lrow] = wv.y;
        Ws[lcol + 2][lrow] = wv.z;
        Ws[lcol + 3][lrow] = wv.w;
        __syncthreads();

#pragma unroll
        for (int kk = 0; kk < BK; ++kk) {
            float4 a0 = *(const float4*)&As[kk][tr];
            float4 a1 = *(const float4*)&As[kk][tr + 4];
            float4 b0 = *(const float4*)&Ws[kk][tc];
            float4 b1 = *(const float4*)&Ws[kk][tc + 4];
            float a[TM] = {a0.x, a0.y, a0.z, a0.w, a1.x, a1.y, a1.z, a1.w};
            float b[TN] = {b0.x, b0.y, b0.z, b0.w, b1.x, b1.y, b1.z, b1.w};
#pragma unroll
            for (int i = 0; i < TM; ++i)
#pragma unroll
                for (int j = 0; j < TN; ++j)
                    acc[i][j] = fmaf(a[i], b[j], acc[i][j]);
        }
    }

    // epilogue
    float bj[TN];
#pragma unroll
    for (int j = 0; j < TN; ++j) bj[j] = bias[bn + tc + j];

#pragma unroll
    for (int i = 0; i < TM; ++i) {
        const size_t r = (size_t)(bm + tr + i) * N + bn + tc;
        float4 v0 = {acc[i][0] + bj[0], acc[i][1] + bj[1],
                     acc[i][2] + bj[2], acc[i][3] + bj[3]};
        float4 v1 = {acc[i][4] + bj[4], acc[i][5] + bj[5],
                     acc[i][6] + bj[6], acc[i][7] + bj[7]};
        *(float4*)&C[r]     = v0;
        *(float4*)&C[r + 4] = v1;
    }
}

// ---------------------------------------------------------------------------
// Depthwise causal conv (k=4) + bias + SiLU.
// Reads x-half of xz [bt, 0:1536], writes xconv[bt, d].
// ---------------------------------------------------------------------------
__global__ __launch_bounds__(256) void conv_silu_kernel(
    const float* __restrict__ xz, const float* __restrict__ cw,
    const float* __restrict__ cb, float* __restrict__ out)
{
    const int idx = blockIdx.x * 256 + threadIdx.x;   // 0 .. 4096*1536
    const int d = idx % D_INNER;
    const int bt = idx / D_INNER;                      // b*SEQ + t
    const int t = bt & (SEQ - 1);

    const float w0 = cw[d * 4 + 0];
    const float w1 = cw[d * 4 + 1];
    const float w2 = cw[d * 4 + 2];
    const float w3 = cw[d * 4 + 3];

    float acc = cb[d];
    const size_t base = (size_t)bt * NXZ + d;
    if (t >= 3) acc = fmaf(xz[base - 3 * (size_t)NXZ], w0, acc);
    if (t >= 2) acc = fmaf(xz[base - 2 * (size_t)NXZ], w1, acc);
    if (t >= 1) acc = fmaf(xz[base - 1 * (size_t)NXZ], w2, acc);
    acc = fmaf(xz[base], w3, acc);

    // SiLU
    const float s = acc / (1.f + __expf(-acc));
    out[idx] = s;
}

// ---------------------------------------------------------------------------
// x-proj: x_ssm[row, 0:33] = xconv[row, :] @ xp_W^T + xp_b. One wave per row.
// ---------------------------------------------------------------------------
__global__ __launch_bounds__(64) void xproj_kernel(
    const float* __restrict__ X, const float* __restrict__ W,
    const float* __restrict__ b, float* __restrict__ out)
{
    const int row = blockIdx.x;
    const int lane = threadIdx.x;

    float xr[24];
#pragma unroll
    for (int i = 0; i < 24; ++i)
        xr[i] = X[(size_t)row * D_INNER + lane + i * 64];

    for (int n = 0; n < NSSM; ++n) {
        float acc = 0.f;
        const float* wrow = W + (size_t)n * D_INNER;
#pragma unroll
        for (int i = 0; i < 24; ++i)
            acc = fmaf(xr[i], wrow[lane + i * 64], acc);
        acc += __shfl_xor(acc, 32);
        acc += __shfl_xor(acc, 16);
        acc += __shfl_xor(acc, 8);
        acc += __shfl_xor(acc, 4);
        acc += __shfl_xor(acc, 2);
        acc += __shfl_xor(acc, 1);
        if (lane == 0) out[(size_t)row * NSSM + n] = acc + b[n];
    }
}

// ---------------------------------------------------------------------------
// Selective scan. One lane per (d, n); 16 lanes = one channel d.
// Block = 64 threads = 4 channels. Grid = BATCH * D_INNER/4 = 768 blocks.
// Writes out_pre = (y + x*D) * silu(z) in-place into xconv.
// ---------------------------------------------------------------------------
__global__ __launch_bounds__(64) void scan_kernel(
    const float* __restrict__ xssm, float* __restrict__ xconv,
    const float* __restrict__ xz, const float* __restrict__ dpW,
    const float* __restrict__ dpb, const float* __restrict__ A_log,
    const float* __restrict__ Dvec)
{
    const int bi = blockIdx.x;
    const int b = bi / (D_INNER / 4);
    const int g = bi - b * (D_INNER / 4);
    const int lane = threadIdx.x;
    const int n = lane & 15;
    const int dl = lane >> 4;             // 0..3
    const int d = g * 4 + dl;

    const float An  = -__expf(A_log[(size_t)d * D_STATE + n]);
    const float w   = dpW[d];
    const float bb  = dpb[d];
    const float Dd  = Dvec[d];

    const float* xssm_b = xssm + (size_t)b * SEQ * NSSM;
    float* xconv_b      = xconv + (size_t)b * SEQ * D_INNER;
    const float* z_b    = xz + (size_t)b * SEQ * NXZ + D_INNER;

    float h = 0.f;

    // preload t=0
    float dr = xssm_b[32];
    float Bt = xssm_b[n];
    float Ct = xssm_b[16 + n];
    float xv = xconv_b[d];
    float zv = z_b[d];

    for (int t = 0; t < SEQ; ++t) {
        const int tn = (t + 1 < SEQ) ? (t + 1) : t;
        // prefetch next step
        const float dr2 = xssm_b[tn * NSSM + 32];
        const float Bt2 = xssm_b[tn * NSSM + n];
        const float Ct2 = xssm_b[tn * NSSM + 16 + n];
        const float xv2 = xconv_b[(size_t)tn * D_INNER + d];
        const float zv2 = z_b[(size_t)tn * NXZ + d];

        // delta = softplus(dr * w + bb)
        const float u = fmaf(dr, w, bb);
        const float delta = __logf(1.f + __expf(u));
        const float dA = __expf(delta * An);
        h = fmaf(dA, h, delta * Bt * xv);

        float p = Ct * h;
        p += __shfl_xor(p, 1);
        p += __shfl_xor(p, 2);
        p += __shfl_xor(p, 4);
        p += __shfl_xor(p, 8);

        if (n == 0) {
            const float yv = fmaf(xv, Dd, p);
            const float sg = zv / (1.f + __expf(-zv));
            xconv_b[(size_t)t * D_INNER + d] = yv * sg;
        }

        dr = dr2; Bt = Bt2; Ct = Ct2; xv = xv2; zv = zv2;
    }
}

// ---------------------------------------------------------------------------
extern "C" void kernel_launch(void* const* d_in, const int* in_sizes, int n_in,
                              void* d_out, int out_size, void* d_ws, size_t ws_size,
                              hipStream_t stream)
{
    const float* x      = (const float*)d_in[0];
    const float* in_W   = (const float*)d_in[1];
    const float* in_b   = (const float*)d_in[2];
    const float* conv_W = (const float*)d_in[3];
    const float* conv_b = (const float*)d_in[4];
    const float* xp_W   = (const float*)d_in[5];
    const float* xp_b   = (const float*)d_in[6];
    const float* dp_W   = (const float*)d_in[7];
    const float* dp_b   = (const float*)d_in[8];
    const float* A_log  = (const float*)d_in[9];
    const float* Dvec   = (const float*)d_in[10];
    const float* out_W  = (const float*)d_in[11];
    const float* out_b  = (const float*)d_in[12];
    float* out = (float*)d_out;

    float* ws    = (float*)d_ws;
    float* xz    = ws;                               // 4096*3072 floats
    float* xconv = ws + (size_t)MROWS * NXZ;         // 4096*1536 floats
    float* xssm  = xconv + (size_t)MROWS * D_INNER;  // 4096*33 floats

    // 1) in-proj GEMM: xz = x @ in_W^T + in_b
    {
        dim3 grid(NXZ / BN, MROWS / BM);
        gemm_tn<<<grid, 256, 0, stream>>>(x, in_W, in_b, xz, MROWS, NXZ, D_MODEL);
    }
    // 2) depthwise conv + SiLU
    {
        const int total = MROWS * D_INNER;
        conv_silu_kernel<<<total / 256, 256, 0, stream>>>(xz, conv_W, conv_b, xconv);
    }
    // 3) x-proj
    xproj_kernel<<<MROWS, 64, 0, stream>>>(xconv, xp_W, xp_b, xssm);
    // 4) selective scan (+ D skip + silu(z) gate), in-place into xconv
    scan_kernel<<<BATCH * (D_INNER / 4), 64, 0, stream>>>(
        xssm, xconv, xz, dp_W, dp_b, A_log, Dvec);
    // 5) out-proj GEMM: out = out_pre @ out_W^T + out_b
    {
        dim3 grid(D_MODEL / BN, MROWS / BM);
        gemm_tn<<<grid, 256, 0, stream>>>(xconv, out_W, out_b, out, MROWS, D_MODEL, D_INNER);
    }
}

// Round 2
// 764.707 us; speedup vs baseline: 1.7598x; 1.7598x over previous
//
#include <hip/hip_runtime.h>
#include <hip/hip_bf16.h>
#include <math.h>

// Problem constants
#define D_MODEL 768
#define D_STATE 16
#define D_CONV  4
#define D_INNER 1536
#define BATCH   2
#define SEQ     2048
#define MROWS   (BATCH * SEQ)        // 4096
#define NXZ     (2 * D_INNER)        // 3072
#define NSSM    (2 * D_STATE + 1)    // 33

// Chunked scan parameters
#define NCH 32                       // chunks over SEQ
#define LCH (SEQ / NCH)              // 64 timesteps per chunk
#define NGRP (D_INNER / 16)          // 96 channel-groups of 16
#define NS  (BATCH * D_INNER * D_STATE)  // 49152 independent streams

// ---------------------------------------------------------------------------
// GEMM: C[M,N] = A[M,K] @ W[N,K]^T + bias[N]   (both A and W are K-contiguous)
// 128x128 tile, BK=8, 256 threads, 8x8 per thread. M,N,K all divide evenly.
// ---------------------------------------------------------------------------
#define BM 128
#define BN 128
#define BK 8
#define TM 8
#define TN 8

__global__ __launch_bounds__(256) void gemm_tn(
    const float* __restrict__ A, const float* __restrict__ W,
    const float* __restrict__ bias, float* __restrict__ C,
    int M, int N, int K)
{
    __shared__ float As[BK][BM];
    __shared__ float Ws[BK][BN];

    const int bm = blockIdx.y * BM;
    const int bn = blockIdx.x * BN;
    const int tid = threadIdx.x;

    const int lrow = tid >> 1;          // 0..127
    const int lcol = (tid & 1) * 4;     // 0 or 4

    const int tr = (tid >> 4) * TM;     // 0..120
    const int tc = (tid & 15) * TN;     // 0..120

    const float* Aptr = A + (size_t)(bm + lrow) * K + lcol;
    const float* Wptr = W + (size_t)(bn + lrow) * K + lcol;

    float acc[TM][TN];
#pragma unroll
    for (int i = 0; i < TM; ++i)
#pragma unroll
        for (int j = 0; j < TN; ++j) acc[i][j] = 0.f;

    for (int k0 = 0; k0 < K; k0 += BK) {
        float4 av = *(const float4*)(Aptr + k0);
        float4 wv = *(const float4*)(Wptr + k0);
        __syncthreads();
        As[lcol + 0][lrow] = av.x;
        As[lcol + 1][lrow] = av.y;
        As[lcol + 2][lrow] = av.z;
        As[lcol + 3][lrow] = av.w;
        Ws[lcol + 0][lrow] = wv.x;
        Ws[lcol + 1][lrow] = wv.y;
        Ws[lcol + 2][lrow] = wv.z;
        Ws[lcol + 3][lrow] = wv.w;
        __syncthreads();

#pragma unroll
        for (int kk = 0; kk < BK; ++kk) {
            float4 a0 = *(const float4*)&As[kk][tr];
            float4 a1 = *(const float4*)&As[kk][tr + 4];
            float4 b0 = *(const float4*)&Ws[kk][tc];
            float4 b1 = *(const float4*)&Ws[kk][tc + 4];
            float a[TM] = {a0.x, a0.y, a0.z, a0.w, a1.x, a1.y, a1.z, a1.w};
            float b[TN] = {b0.x, b0.y, b0.z, b0.w, b1.x, b1.y, b1.z, b1.w};
#pragma unroll
            for (int i = 0; i < TM; ++i)
#pragma unroll
                for (int j = 0; j < TN; ++j)
                    acc[i][j] = fmaf(a[i], b[j], acc[i][j]);
        }
    }

    float bj[TN];
#pragma unroll
    for (int j = 0; j < TN; ++j) bj[j] = bias[bn + tc + j];

#pragma unroll
    for (int i = 0; i < TM; ++i) {
        const size_t r = (size_t)(bm + tr + i) * N + bn + tc;
        float4 v0 = {acc[i][0] + bj[0], acc[i][1] + bj[1],
                     acc[i][2] + bj[2], acc[i][3] + bj[3]};
        float4 v1 = {acc[i][4] + bj[4], acc[i][5] + bj[5],
                     acc[i][6] + bj[6], acc[i][7] + bj[7]};
        *(float4*)&C[r]     = v0;
        *(float4*)&C[r + 4] = v1;
    }
}

// ---------------------------------------------------------------------------
// Depthwise causal conv (k=4) + bias + SiLU.  xconv[bt, d]
// ---------------------------------------------------------------------------
__global__ __launch_bounds__(256) void conv_silu_kernel(
    const float* __restrict__ xz, const float* __restrict__ cw,
    const float* __restrict__ cb, float* __restrict__ out)
{
    const int idx = blockIdx.x * 256 + threadIdx.x;
    const int d = idx % D_INNER;
    const int bt = idx / D_INNER;
    const int t = bt & (SEQ - 1);

    const float w0 = cw[d * 4 + 0];
    const float w1 = cw[d * 4 + 1];
    const float w2 = cw[d * 4 + 2];
    const float w3 = cw[d * 4 + 3];

    float acc = cb[d];
    const size_t base = (size_t)bt * NXZ + d;
    if (t >= 3) acc = fmaf(xz[base - 3 * (size_t)NXZ], w0, acc);
    if (t >= 2) acc = fmaf(xz[base - 2 * (size_t)NXZ], w1, acc);
    if (t >= 1) acc = fmaf(xz[base - 1 * (size_t)NXZ], w2, acc);
    acc = fmaf(xz[base], w3, acc);

    const float s = acc / (1.f + __expf(-acc));
    out[idx] = s;
}

// ---------------------------------------------------------------------------
// x-proj: x_ssm[row, 0:33] = xconv[row, :] @ xp_W^T + xp_b. One wave per row.
// ---------------------------------------------------------------------------
__global__ __launch_bounds__(64) void xproj_kernel(
    const float* __restrict__ X, const float* __restrict__ W,
    const float* __restrict__ b, float* __restrict__ out)
{
    const int row = blockIdx.x;
    const int lane = threadIdx.x;

    float xr[24];
#pragma unroll
    for (int i = 0; i < 24; ++i)
        xr[i] = X[(size_t)row * D_INNER + lane + i * 64];

    for (int n = 0; n < NSSM; ++n) {
        float acc = 0.f;
        const float* wrow = W + (size_t)n * D_INNER;
#pragma unroll
        for (int i = 0; i < 24; ++i)
            acc = fmaf(xr[i], wrow[lane + i * 64], acc);
        acc += __shfl_xor(acc, 32);
        acc += __shfl_xor(acc, 16);
        acc += __shfl_xor(acc, 8);
        acc += __shfl_xor(acc, 4);
        acc += __shfl_xor(acc, 2);
        acc += __shfl_xor(acc, 1);
        if (lane == 0) out[(size_t)row * NSSM + n] = acc + b[n];
    }
}

// ---------------------------------------------------------------------------
// Chunked selective scan, 3 phases.
// Streams: (b, d, n), NS = 49152.  Stream id s = (b*1536 + d)*16 + n.
// Block = 256 threads = 16 channels x 16 states; lane tid: n=tid&15,
// ch=tid>>4, d=g*16+ch.  Per-block stream ids are contiguous:
// s = (b*96+g)*256 + tid.
// ---------------------------------------------------------------------------

// Phase 1: per-chunk local scan from h=0; store A-product and local h_end.
__global__ __launch_bounds__(256) void scan_phase1(
    const float* __restrict__ xssm, const float* __restrict__ xconv,
    const float* __restrict__ dpW, const float* __restrict__ dpb,
    const float* __restrict__ A_log,
    float* __restrict__ Ap, float* __restrict__ Hp)
{
    __shared__ float s_x[LCH * NSSM];     // 64*33 = 2112 floats
    __shared__ float s_xv[16 * 68];       // padded stride 68

    const int g = blockIdx.x;             // 0..95
    const int c = blockIdx.y;             // 0..31
    const int b = blockIdx.z;             // 0..1
    const int tid = threadIdx.x;
    const int n = tid & 15;
    const int ch = tid >> 4;              // 0..15
    const int d = g * 16 + ch;

    const float An = -__expf(A_log[d * D_STATE + n]);
    const float w  = dpW[d];
    const float bb = dpb[d];

    const size_t bt0 = (size_t)b * SEQ + c * LCH;

    // stage xssm chunk (contiguous LCH*33 floats)
    {
        const float* src = xssm + bt0 * NSSM;
        for (int i = tid; i < LCH * NSSM; i += 256) s_x[i] = src[i];
    }
    // stage xv: 16 consecutive lanes read 16 consecutive d (same 64B line)
    {
        const int cc = tid & 15;
        const int tq = tid >> 4;
#pragma unroll
        for (int i = 0; i < 4; ++i) {
            const int t = tq * 4 + i;
            s_xv[cc * 68 + t] = xconv[(bt0 + t) * (size_t)D_INNER + g * 16 + cc];
        }
    }
    __syncthreads();

    float h = 0.f, ap = 1.f;
#pragma unroll 4
    for (int t = 0; t < LCH; ++t) {
        const float dr = s_x[t * NSSM + 32];
        const float Bt = s_x[t * NSSM + n];
        const float xv = s_xv[ch * 68 + t];
        const float u  = fmaf(dr, w, bb);
        const float delta = __logf(1.f + __expf(u));
        const float dA = __expf(delta * An);
        h = fmaf(dA, h, delta * Bt * xv);
        ap *= dA;
    }

    const size_t s = (size_t)(b * NGRP + g) * 256 + tid;
    Ap[(size_t)c * NS + s] = ap;
    Hp[(size_t)c * NS + s] = h;
}

// Phase 2: serial prefix over chunk summaries; Hs[c] = h at chunk-c start.
__global__ __launch_bounds__(256) void scan_phase2(
    const float* __restrict__ Ap, const float* __restrict__ Hp,
    float* __restrict__ Hs)
{
    const size_t s = (size_t)blockIdx.x * 256 + threadIdx.x;
    float carry = 0.f;
    float a_nxt = Ap[s], h_nxt = Hp[s];
    for (int c = 0; c < NCH; ++c) {
        const float a = a_nxt, hp = h_nxt;
        if (c + 1 < NCH) {
            a_nxt = Ap[(size_t)(c + 1) * NS + s];
            h_nxt = Hp[(size_t)(c + 1) * NS + s];
        }
        Hs[(size_t)c * NS + s] = carry;
        carry = fmaf(a, carry, hp);
    }
}

// Phase 3: replay each chunk with the correct h_start; emit gated output
// in-place into xconv[bt, d].
__global__ __launch_bounds__(256) void scan_phase3(
    const float* __restrict__ xssm, float* __restrict__ xconv,
    const float* __restrict__ xz,
    const float* __restrict__ dpW, const float* __restrict__ dpb,
    const float* __restrict__ A_log, const float* __restrict__ Dvec,
    const float* __restrict__ Hs)
{
    __shared__ float s_x[LCH * NSSM];
    __shared__ float s_xv[16 * 68];
    __shared__ float s_z[16 * 68];

    const int g = blockIdx.x;
    const int c = blockIdx.y;
    const int b = blockIdx.z;
    const int tid = threadIdx.x;
    const int n = tid & 15;
    const int ch = tid >> 4;
    const int d = g * 16 + ch;

    const float An = -__expf(A_log[d * D_STATE + n]);
    const float w  = dpW[d];
    const float bb = dpb[d];
    const float Dd = Dvec[d];

    const size_t bt0 = (size_t)b * SEQ + c * LCH;

    {
        const float* src = xssm + bt0 * NSSM;
        for (int i = tid; i < LCH * NSSM; i += 256) s_x[i] = src[i];
    }
    {
        const int cc = tid & 15;
        const int tq = tid >> 4;
#pragma unroll
        for (int i = 0; i < 4; ++i) {
            const int t = tq * 4 + i;
            s_xv[cc * 68 + t] = xconv[(bt0 + t) * (size_t)D_INNER + g * 16 + cc];
            s_z[cc * 68 + t]  = xz[(bt0 + t) * (size_t)NXZ + D_INNER + g * 16 + cc];
        }
    }
    __syncthreads();

    const size_t s = (size_t)(b * NGRP + g) * 256 + tid;
    float h = Hs[(size_t)c * NS + s];

    for (int t = 0; t < LCH; ++t) {
        const float dr = s_x[t * NSSM + 32];
        const float Bt = s_x[t * NSSM + n];
        const float Ct = s_x[t * NSSM + 16 + n];
        const float xv = s_xv[ch * 68 + t];
        const float u  = fmaf(dr, w, bb);
        const float delta = __logf(1.f + __expf(u));
        const float dA = __expf(delta * An);
        h = fmaf(dA, h, delta * Bt * xv);

        float p = Ct * h;
        p += __shfl_xor(p, 1);
        p += __shfl_xor(p, 2);
        p += __shfl_xor(p, 4);
        p += __shfl_xor(p, 8);

        if (n == 0) {
            const float zv = s_z[ch * 68 + t];
            const float yv = fmaf(xv, Dd, p);
            const float sg = zv / (1.f + __expf(-zv));
            xconv[(bt0 + t) * (size_t)D_INNER + d] = yv * sg;
        }
    }
}

// ---------------------------------------------------------------------------
extern "C" void kernel_launch(void* const* d_in, const int* in_sizes, int n_in,
                              void* d_out, int out_size, void* d_ws, size_t ws_size,
                              hipStream_t stream)
{
    const float* x      = (const float*)d_in[0];
    const float* in_W   = (const float*)d_in[1];
    const float* in_b   = (const float*)d_in[2];
    const float* conv_W = (const float*)d_in[3];
    const float* conv_b = (const float*)d_in[4];
    const float* xp_W   = (const float*)d_in[5];
    const float* xp_b   = (const float*)d_in[6];
    const float* dp_W   = (const float*)d_in[7];
    const float* dp_b   = (const float*)d_in[8];
    const float* A_log  = (const float*)d_in[9];
    const float* Dvec   = (const float*)d_in[10];
    const float* out_W  = (const float*)d_in[11];
    const float* out_b  = (const float*)d_in[12];
    float* out = (float*)d_out;

    float* ws    = (float*)d_ws;
    float* xz    = ws;                                // 4096*3072
    float* xconv = xz + (size_t)MROWS * NXZ;          // 4096*1536
    float* xssm  = xconv + (size_t)MROWS * D_INNER;   // 4096*33
    float* Ap    = xssm + (size_t)MROWS * NSSM;       // NCH*NS
    float* Hp    = Ap + (size_t)NCH * NS;             // NCH*NS
    float* Hs    = Hp + (size_t)NCH * NS;             // NCH*NS

    // 1) in-proj GEMM: xz = x @ in_W^T + in_b
    {
        dim3 grid(NXZ / BN, MROWS / BM);
        gemm_tn<<<grid, 256, 0, stream>>>(x, in_W, in_b, xz, MROWS, NXZ, D_MODEL);
    }
    // 2) depthwise conv + SiLU
    {
        const int total = MROWS * D_INNER;
        conv_silu_kernel<<<total / 256, 256, 0, stream>>>(xz, conv_W, conv_b, xconv);
    }
    // 3) x-proj
    xproj_kernel<<<MROWS, 64, 0, stream>>>(xconv, xp_W, xp_b, xssm);
    // 4) chunked selective scan
    {
        dim3 grid13(NGRP, NCH, BATCH);
        scan_phase1<<<grid13, 256, 0, stream>>>(xssm, xconv, dp_W, dp_b, A_log, Ap, Hp);
        scan_phase2<<<NS / 256, 256, 0, stream>>>(Ap, Hp, Hs);
        scan_phase3<<<grid13, 256, 0, stream>>>(xssm, xconv, xz, dp_W, dp_b, A_log,
                                                Dvec, Hs);
    }
    // 5) out-proj GEMM: out = xconv @ out_W^T + out_b
    {
        dim3 grid(D_MODEL / BN, MROWS / BM);
        gemm_tn<<<grid, 256, 0, stream>>>(xconv, out_W, out_b, out, MROWS, D_MODEL, D_INNER);
    }
}

// Round 3
// 468.293 us; speedup vs baseline: 2.8737x; 1.6330x over previous
//
#include <hip/hip_runtime.h>
#include <hip/hip_bf16.h>
#include <math.h>

// Problem constants
#define D_MODEL 768
#define D_STATE 16
#define D_CONV  4
#define D_INNER 1536
#define BATCH   2
#define SEQ     2048
#define MROWS   (BATCH * SEQ)        // 4096
#define NXZ     (2 * D_INNER)        // 3072
#define NSSM    (2 * D_STATE + 1)    // 33

// Chunked scan parameters
#define NCH 32
#define LCH (SEQ / NCH)              // 64
#define NGRP (D_INNER / 16)          // 96
#define NS  (BATCH * D_INNER * D_STATE)  // 49152

typedef short s8v __attribute__((ext_vector_type(8)));   // 8 bf16 (4 VGPRs)
typedef float f4v __attribute__((ext_vector_type(4)));   // 4 fp32 acc

// ---------------------------------------------------------------------------
// bf16 split helpers (manual RNE, avoids header type plumbing)
// ---------------------------------------------------------------------------
__device__ __forceinline__ unsigned short f2bf_rne(float f) {
    unsigned int x = __float_as_uint(f);
    unsigned int r = (x + 0x7FFFu + ((x >> 16) & 1u)) >> 16;
    return (unsigned short)r;
}
__device__ __forceinline__ float bf2f(unsigned short h) {
    return __uint_as_float(((unsigned int)h) << 16);
}

__device__ __forceinline__ void gl_lds16(const unsigned short* g, unsigned short* l) {
    __builtin_amdgcn_global_load_lds(
        (const __attribute__((address_space(1))) void*)g,
        (__attribute__((address_space(3))) void*)l, 16, 0, 0);
}

// ---------------------------------------------------------------------------
// split_retile: src fp32 [R x K] row-major  ->  dh/dl bf16 in GEMM-tiled
// layout:  off(m,k) = ((kb*(R/16) + mb)*16 + mr)*32 + (kc ^ ((mr>>1)&3))*8 + kj
// where kb=k>>5, kc=(k>>3)&3, kj=k&7, mb=m>>4, mr=m&15.
// This is exactly the LDS image gemm_split stages with global_load_lds, with
// the bank-conflict XOR swizzle baked in.
// ---------------------------------------------------------------------------
__global__ __launch_bounds__(256) void split_retile(
    const float* __restrict__ src, unsigned short* __restrict__ dh,
    unsigned short* __restrict__ dl, int R, int K)
{
    const int o = blockIdx.x * 256 + threadIdx.x;
    const int kj = o & 7;
    const int cp = (o >> 3) & 3;
    const int mr = (o >> 5) & 15;
    const int rest = o >> 9;
    const int Rb = R >> 4;
    const int mb = rest % Rb;
    const int kb = rest / Rb;
    const int kc = cp ^ ((mr >> 1) & 3);
    const int m = (mb << 4) + mr;
    const int k = (kb << 5) + (kc << 3) + kj;
    const float v = src[(size_t)m * K + k];
    const unsigned short h = f2bf_rne(v);
    dh[o] = h;
    dl[o] = f2bf_rne(v - bf2f(h));
}

// ---------------------------------------------------------------------------
// Split-bf16 MFMA GEMM: C[M,N] = A[M,K] @ W[N,K]^T + bias
// A,W pre-split (hi/lo) and pre-retiled (see split_retile).
// 256 threads = 4 waves in a 2x2 grid; wave tile = (BMt/2) x (BNt/2);
// MT = BMt/32, NT = BNt/32 tiles of 16x16 per wave; K staged 32 per step.
// ---------------------------------------------------------------------------
template<int BMt, int BNt>
__global__ __launch_bounds__(256) void gemm_split(
    const unsigned short* __restrict__ Ah, const unsigned short* __restrict__ Al,
    const unsigned short* __restrict__ Bh, const unsigned short* __restrict__ Bl,
    const float* __restrict__ bias, float* __restrict__ C,
    int M, int N, int K)
{
    constexpr int MT = BMt / 32;
    constexpr int NT = BNt / 32;

    __shared__ unsigned short lsAh[BMt * 32];
    __shared__ unsigned short lsAl[BMt * 32];
    __shared__ unsigned short lsBh[BNt * 32];
    __shared__ unsigned short lsBl[BNt * 32];

    const int tid = threadIdx.x;
    const int w = tid >> 6, lane = tid & 63;
    const int wr = w >> 1, wc = w & 1;
    const int row16 = lane & 15, quad = lane >> 4;
    const int bm = blockIdx.y, bn = blockIdx.x;
    const int Mb = M >> 4, Nb = N >> 4;
    const int mb0 = bm * (BMt / 16), nb0 = bn * (BNt / 16);

    f4v acc[MT][NT];
    const f4v zero4 = {0.f, 0.f, 0.f, 0.f};
#pragma unroll
    for (int i = 0; i < MT; ++i)
#pragma unroll
        for (int j = 0; j < NT; ++j) acc[i][j] = zero4;

    const int swz = (row16 >> 1) & 3;
    int aoff[MT], boff[NT];
#pragma unroll
    for (int i = 0; i < MT; ++i)
        aoff[i] = (((wr * MT + i) * 16 + row16) << 5) + ((quad ^ swz) << 3);
#pragma unroll
    for (int j = 0; j < NT; ++j)
        boff[j] = (((wc * NT + j) * 16 + row16) << 5) + ((quad ^ swz) << 3);

    const int nkb = K >> 5;
    for (int kb = 0; kb < nkb; ++kb) {
        __syncthreads();
        {
            const size_t ka = (size_t)kb * Mb + mb0;
#pragma unroll
            for (int c = w; c < BMt / 16; c += 4) {
                gl_lds16(Ah + ((ka + c) << 9) + lane * 8, &lsAh[c << 9]);
                gl_lds16(Al + ((ka + c) << 9) + lane * 8, &lsAl[c << 9]);
            }
            const size_t kB = (size_t)kb * Nb + nb0;
#pragma unroll
            for (int c = w; c < BNt / 16; c += 4) {
                gl_lds16(Bh + ((kB + c) << 9) + lane * 8, &lsBh[c << 9]);
                gl_lds16(Bl + ((kB + c) << 9) + lane * 8, &lsBl[c << 9]);
            }
        }
        __syncthreads();

        s8v ah[MT], al[MT], bh[NT], bl[NT];
#pragma unroll
        for (int i = 0; i < MT; ++i) {
            ah[i] = *(const s8v*)&lsAh[aoff[i]];
            al[i] = *(const s8v*)&lsAl[aoff[i]];
        }
#pragma unroll
        for (int j = 0; j < NT; ++j) {
            bh[j] = *(const s8v*)&lsBh[boff[j]];
            bl[j] = *(const s8v*)&lsBl[boff[j]];
        }
#pragma unroll
        for (int i = 0; i < MT; ++i)
#pragma unroll
            for (int j = 0; j < NT; ++j) {
                acc[i][j] = __builtin_amdgcn_mfma_f32_16x16x32_bf16(
                    al[i], bh[j], acc[i][j], 0, 0, 0);
                acc[i][j] = __builtin_amdgcn_mfma_f32_16x16x32_bf16(
                    ah[i], bl[j], acc[i][j], 0, 0, 0);
                acc[i][j] = __builtin_amdgcn_mfma_f32_16x16x32_bf16(
                    ah[i], bh[j], acc[i][j], 0, 0, 0);
            }
    }

    // epilogue: C[row][col] with col=lane&15, row=quad*4+reg (m89-verified)
#pragma unroll
    for (int j = 0; j < NT; ++j) {
        const int col = bn * BNt + (wc * NT + j) * 16 + row16;
        const float bc = bias[col];
#pragma unroll
        for (int i = 0; i < MT; ++i) {
            const int row0 = bm * BMt + (wr * MT + i) * 16 + quad * 4;
#pragma unroll
            for (int r = 0; r < 4; ++r)
                C[(size_t)(row0 + r) * N + col] = acc[i][j][r] + bc;
        }
    }
}

// ---------------------------------------------------------------------------
// Depthwise causal conv (k=4) + bias + SiLU.  xconv[bt, d]
// ---------------------------------------------------------------------------
__global__ __launch_bounds__(256) void conv_silu_kernel(
    const float* __restrict__ xz, const float* __restrict__ cw,
    const float* __restrict__ cb, float* __restrict__ out)
{
    const int idx = blockIdx.x * 256 + threadIdx.x;
    const int d = idx % D_INNER;
    const int bt = idx / D_INNER;
    const int t = bt & (SEQ - 1);

    const float w0 = cw[d * 4 + 0];
    const float w1 = cw[d * 4 + 1];
    const float w2 = cw[d * 4 + 2];
    const float w3 = cw[d * 4 + 3];

    float acc = cb[d];
    const size_t base = (size_t)bt * NXZ + d;
    if (t >= 3) acc = fmaf(xz[base - 3 * (size_t)NXZ], w0, acc);
    if (t >= 2) acc = fmaf(xz[base - 2 * (size_t)NXZ], w1, acc);
    if (t >= 1) acc = fmaf(xz[base - 1 * (size_t)NXZ], w2, acc);
    acc = fmaf(xz[base], w3, acc);

    out[idx] = acc / (1.f + __expf(-acc));
}

// ---------------------------------------------------------------------------
// x-proj: x_ssm[row, 0:33] = xconv[row, :] @ xp_W^T + xp_b. One wave per row.
// ---------------------------------------------------------------------------
__global__ __launch_bounds__(64) void xproj_kernel(
    const float* __restrict__ X, const float* __restrict__ W,
    const float* __restrict__ b, float* __restrict__ out)
{
    const int row = blockIdx.x;
    const int lane = threadIdx.x;

    float xr[24];
#pragma unroll
    for (int i = 0; i < 24; ++i)
        xr[i] = X[(size_t)row * D_INNER + lane + i * 64];

    for (int n = 0; n < NSSM; ++n) {
        float acc = 0.f;
        const float* wrow = W + (size_t)n * D_INNER;
#pragma unroll
        for (int i = 0; i < 24; ++i)
            acc = fmaf(xr[i], wrow[lane + i * 64], acc);
        acc += __shfl_xor(acc, 32);
        acc += __shfl_xor(acc, 16);
        acc += __shfl_xor(acc, 8);
        acc += __shfl_xor(acc, 4);
        acc += __shfl_xor(acc, 2);
        acc += __shfl_xor(acc, 1);
        if (lane == 0) out[(size_t)row * NSSM + n] = acc + b[n];
    }
}

// ---------------------------------------------------------------------------
// Chunked selective scan (3 phases), as round 2 (verified).
// ---------------------------------------------------------------------------
__global__ __launch_bounds__(256) void scan_phase1(
    const float* __restrict__ xssm, const float* __restrict__ xconv,
    const float* __restrict__ dpW, const float* __restrict__ dpb,
    const float* __restrict__ A_log,
    float* __restrict__ Ap, float* __restrict__ Hp)
{
    __shared__ float s_x[LCH * NSSM];
    __shared__ float s_xv[16 * 68];

    const int g = blockIdx.x;
    const int c = blockIdx.y;
    const int b = blockIdx.z;
    const int tid = threadIdx.x;
    const int n = tid & 15;
    const int ch = tid >> 4;
    const int d = g * 16 + ch;

    const float An = -__expf(A_log[d * D_STATE + n]);
    const float w  = dpW[d];
    const float bb = dpb[d];

    const size_t bt0 = (size_t)b * SEQ + c * LCH;

    {
        const float* src = xssm + bt0 * NSSM;
        for (int i = tid; i < LCH * NSSM; i += 256) s_x[i] = src[i];
    }
    {
        const int cc = tid & 15;
        const int tq = tid >> 4;
#pragma unroll
        for (int i = 0; i < 4; ++i) {
            const int t = tq * 4 + i;
            s_xv[cc * 68 + t] = xconv[(bt0 + t) * (size_t)D_INNER + g * 16 + cc];
        }
    }
    __syncthreads();

    float h = 0.f, ap = 1.f;
#pragma unroll 4
    for (int t = 0; t < LCH; ++t) {
        const float dr = s_x[t * NSSM + 32];
        const float Bt = s_x[t * NSSM + n];
        const float xv = s_xv[ch * 68 + t];
        const float u  = fmaf(dr, w, bb);
        const float delta = __logf(1.f + __expf(u));
        const float dA = __expf(delta * An);
        h = fmaf(dA, h, delta * Bt * xv);
        ap *= dA;
    }

    const size_t s = (size_t)(b * NGRP + g) * 256 + tid;
    Ap[(size_t)c * NS + s] = ap;
    Hp[(size_t)c * NS + s] = h;
}

// Phase 2: serial prefix over chunk summaries; writes h-at-chunk-start
// IN PLACE into Ap (read-before-write per thread, safe).
__global__ __launch_bounds__(256) void scan_phase2(
    float* __restrict__ Ap, const float* __restrict__ Hp)
{
    const size_t s = (size_t)blockIdx.x * 256 + threadIdx.x;
    float carry = 0.f;
    for (int c = 0; c < NCH; ++c) {
        const float a  = Ap[(size_t)c * NS + s];
        const float hp = Hp[(size_t)c * NS + s];
        Ap[(size_t)c * NS + s] = carry;
        carry = fmaf(a, carry, hp);
    }
}

__global__ __launch_bounds__(256) void scan_phase3(
    const float* __restrict__ xssm, float* __restrict__ xconv,
    const float* __restrict__ xz,
    const float* __restrict__ dpW, const float* __restrict__ dpb,
    const float* __restrict__ A_log, const float* __restrict__ Dvec,
    const float* __restrict__ Hs)
{
    __shared__ float s_x[LCH * NSSM];
    __shared__ float s_xv[16 * 68];
    __shared__ float s_z[16 * 68];

    const int g = blockIdx.x;
    const int c = blockIdx.y;
    const int b = blockIdx.z;
    const int tid = threadIdx.x;
    const int n = tid & 15;
    const int ch = tid >> 4;
    const int d = g * 16 + ch;

    const float An = -__expf(A_log[d * D_STATE + n]);
    const float w  = dpW[d];
    const float bb = dpb[d];
    const float Dd = Dvec[d];

    const size_t bt0 = (size_t)b * SEQ + c * LCH;

    {
        const float* src = xssm + bt0 * NSSM;
        for (int i = tid; i < LCH * NSSM; i += 256) s_x[i] = src[i];
    }
    {
        const int cc = tid & 15;
        const int tq = tid >> 4;
#pragma unroll
        for (int i = 0; i < 4; ++i) {
            const int t = tq * 4 + i;
            s_xv[cc * 68 + t] = xconv[(bt0 + t) * (size_t)D_INNER + g * 16 + cc];
            s_z[cc * 68 + t]  = xz[(bt0 + t) * (size_t)NXZ + D_INNER + g * 16 + cc];
        }
    }
    __syncthreads();

    const size_t s = (size_t)(b * NGRP + g) * 256 + tid;
    float h = Hs[(size_t)c * NS + s];

    for (int t = 0; t < LCH; ++t) {
        const float dr = s_x[t * NSSM + 32];
        const float Bt = s_x[t * NSSM + n];
        const float Ct = s_x[t * NSSM + 16 + n];
        const float xv = s_xv[ch * 68 + t];
        const float u  = fmaf(dr, w, bb);
        const float delta = __logf(1.f + __expf(u));
        const float dA = __expf(delta * An);
        h = fmaf(dA, h, delta * Bt * xv);

        float p = Ct * h;
        p += __shfl_xor(p, 1);
        p += __shfl_xor(p, 2);
        p += __shfl_xor(p, 4);
        p += __shfl_xor(p, 8);

        if (n == 0) {
            const float zv = s_z[ch * 68 + t];
            const float yv = fmaf(xv, Dd, p);
            const float sg = zv / (1.f + __expf(-zv));
            xconv[(bt0 + t) * (size_t)D_INNER + d] = yv * sg;
        }
    }
}

// ---------------------------------------------------------------------------
extern "C" void kernel_launch(void* const* d_in, const int* in_sizes, int n_in,
                              void* d_out, int out_size, void* d_ws, size_t ws_size,
                              hipStream_t stream)
{
    const float* x      = (const float*)d_in[0];
    const float* in_W   = (const float*)d_in[1];
    const float* in_b   = (const float*)d_in[2];
    const float* conv_W = (const float*)d_in[3];
    const float* conv_b = (const float*)d_in[4];
    const float* xp_W   = (const float*)d_in[5];
    const float* xp_b   = (const float*)d_in[6];
    const float* dp_W   = (const float*)d_in[7];
    const float* dp_b   = (const float*)d_in[8];
    const float* A_log  = (const float*)d_in[9];
    const float* Dvec   = (const float*)d_in[10];
    const float* out_W  = (const float*)d_in[11];
    const float* out_b  = (const float*)d_in[12];
    float* out = (float*)d_out;

    // workspace layout (float units)
    float* ws    = (float*)d_ws;
    float* xz    = ws;                                       // 12,582,912
    float* xconv = xz + (size_t)MROWS * NXZ;                 //  6,291,456
    float* xssm  = xconv + (size_t)MROWS * D_INNER;          //    135,168
    float* Ap    = xssm + (size_t)MROWS * NSSM;              //  1,572,864 (Hs in-place)
    float* Hp    = Ap + (size_t)NCH * NS;                    //  1,572,864
    unsigned short* inWh  = (unsigned short*)(Hp + (size_t)NCH * NS);
    unsigned short* inWl  = inWh + (size_t)NXZ * D_MODEL;    // 2,359,296 shorts each
    unsigned short* outWh = inWl + (size_t)NXZ * D_MODEL;
    unsigned short* outWl = outWh + (size_t)D_MODEL * D_INNER; // 1,179,648 shorts each

    // x-split lives in d_out (scratch until the final GEMM writes it)
    unsigned short* xh = (unsigned short*)d_out;             // 3,145,728 shorts
    unsigned short* xl = xh + (size_t)MROWS * D_MODEL;
    // xcg-split aliases the (dead-after-phase3) xz region
    unsigned short* xcgh = (unsigned short*)xz;              // 6,291,456 shorts
    unsigned short* xcgl = xcgh + (size_t)MROWS * D_INNER;

    // 0) split+retile x, in_W, out_W
    split_retile<<<(MROWS * D_MODEL) / 256, 256, 0, stream>>>(x, xh, xl, MROWS, D_MODEL);
    split_retile<<<(NXZ * D_MODEL) / 256, 256, 0, stream>>>(in_W, inWh, inWl, NXZ, D_MODEL);
    split_retile<<<(D_MODEL * D_INNER) / 256, 256, 0, stream>>>(out_W, outWh, outWl, D_MODEL, D_INNER);

    // 1) in-proj: xz = x @ in_W^T + in_b   (M=4096, N=3072, K=768)
    {
        dim3 grid(NXZ / 128, MROWS / 128);
        gemm_split<128, 128><<<grid, 256, 0, stream>>>(
            xh, xl, inWh, inWl, in_b, xz, MROWS, NXZ, D_MODEL);
    }
    // 2) depthwise conv + SiLU
    conv_silu_kernel<<<(MROWS * D_INNER) / 256, 256, 0, stream>>>(xz, conv_W, conv_b, xconv);
    // 3) x-proj
    xproj_kernel<<<MROWS, 64, 0, stream>>>(xconv, xp_W, xp_b, xssm);
    // 4) chunked selective scan
    {
        dim3 grid13(NGRP, NCH, BATCH);
        scan_phase1<<<grid13, 256, 0, stream>>>(xssm, xconv, dp_W, dp_b, A_log, Ap, Hp);
        scan_phase2<<<NS / 256, 256, 0, stream>>>(Ap, Hp);
        scan_phase3<<<grid13, 256, 0, stream>>>(xssm, xconv, xz, dp_W, dp_b, A_log,
                                                Dvec, Ap);
    }
    // 5) split+retile gated output (xz region is dead now)
    split_retile<<<(MROWS * D_INNER) / 256, 256, 0, stream>>>(xconv, xcgh, xcgl, MROWS, D_INNER);
    // 6) out-proj: out = y @ out_W^T + out_b  (M=4096, N=768, K=1536)
    {
        dim3 grid(D_MODEL / 64, MROWS / 64);
        gemm_split<64, 64><<<grid, 256, 0, stream>>>(
            xcgh, xcgl, outWh, outWl, out_b, out, MROWS, D_MODEL, D_INNER);
    }
}

// Round 4
// 353.729 us; speedup vs baseline: 3.8045x; 1.3239x over previous
//
#include <hip/hip_runtime.h>
#include <hip/hip_bf16.h>
#include <math.h>

// Problem constants
#define D_MODEL 768
#define D_STATE 16
#define D_CONV  4
#define D_INNER 1536
#define BATCH   2
#define SEQ     2048
#define MROWS   (BATCH * SEQ)        // 4096
#define NXZ     (2 * D_INNER)        // 3072
#define NSSM    (2 * D_STATE + 1)    // 33
#define BD      (BATCH * D_INNER)    // 3072

// Chunked scan parameters
#define NCH 64
#define LCH (SEQ / NCH)              // 32
#define NS  (BATCH * D_INNER * D_STATE)  // 49152

typedef short s8v __attribute__((ext_vector_type(8)));   // 8 bf16 (4 VGPRs)
typedef float f4v __attribute__((ext_vector_type(4)));   // 4 fp32 acc

// ---------------------------------------------------------------------------
// bf16 split helpers
// ---------------------------------------------------------------------------
__device__ __forceinline__ unsigned short f2bf_rne(float f) {
    unsigned int x = __float_as_uint(f);
    unsigned int r = (x + 0x7FFFu + ((x >> 16) & 1u)) >> 16;
    return (unsigned short)r;
}
__device__ __forceinline__ float bf2f(unsigned short h) {
    return __uint_as_float(((unsigned int)h) << 16);
}

__device__ __forceinline__ void gl_lds16(const unsigned short* g, unsigned short* l) {
    __builtin_amdgcn_global_load_lds(
        (const __attribute__((address_space(1))) void*)g,
        (__attribute__((address_space(3))) void*)l, 16, 0, 0);
}

// ---------------------------------------------------------------------------
// split_retile: src fp32 [R x K] row-major -> dh/dl bf16 in GEMM-tiled layout
// off(m,k) = ((kb*(R/16)+mb)*16+mr)*32 + (kc ^ ((mr>>1)&3))*8 + kj
// ---------------------------------------------------------------------------
__global__ __launch_bounds__(256) void split_retile(
    const float* __restrict__ src, unsigned short* __restrict__ dh,
    unsigned short* __restrict__ dl, int R, int K)
{
    const int o = blockIdx.x * 256 + threadIdx.x;
    const int kj = o & 7;
    const int cp = (o >> 3) & 3;
    const int mr = (o >> 5) & 15;
    const int rest = o >> 9;
    const int Rb = R >> 4;
    const int mb = rest % Rb;
    const int kb = rest / Rb;
    const int kc = cp ^ ((mr >> 1) & 3);
    const int m = (mb << 4) + mr;
    const int k = (kb << 5) + (kc << 3) + kj;
    const float v = src[(size_t)m * K + k];
    const unsigned short h = f2bf_rne(v);
    dh[o] = h;
    dl[o] = f2bf_rne(v - bf2f(h));
}

// ---------------------------------------------------------------------------
// Split-bf16 MFMA GEMM: C[M,N] = A[M,K] @ W[N,K]^T + bias (pre-retiled A,W)
// ---------------------------------------------------------------------------
template<int BMt, int BNt>
__global__ __launch_bounds__(256) void gemm_split(
    const unsigned short* __restrict__ Ah, const unsigned short* __restrict__ Al,
    const unsigned short* __restrict__ Bh, const unsigned short* __restrict__ Bl,
    const float* __restrict__ bias, float* __restrict__ C,
    int M, int N, int K)
{
    constexpr int MT = BMt / 32;
    constexpr int NT = BNt / 32;

    __shared__ unsigned short lsAh[BMt * 32];
    __shared__ unsigned short lsAl[BMt * 32];
    __shared__ unsigned short lsBh[BNt * 32];
    __shared__ unsigned short lsBl[BNt * 32];

    const int tid = threadIdx.x;
    const int w = tid >> 6, lane = tid & 63;
    const int wr = w >> 1, wc = w & 1;
    const int row16 = lane & 15, quad = lane >> 4;
    const int bm = blockIdx.y, bn = blockIdx.x;
    const int Mb = M >> 4, Nb = N >> 4;
    const int mb0 = bm * (BMt / 16), nb0 = bn * (BNt / 16);

    f4v acc[MT][NT];
    const f4v zero4 = {0.f, 0.f, 0.f, 0.f};
#pragma unroll
    for (int i = 0; i < MT; ++i)
#pragma unroll
        for (int j = 0; j < NT; ++j) acc[i][j] = zero4;

    const int swz = (row16 >> 1) & 3;
    int aoff[MT], boff[NT];
#pragma unroll
    for (int i = 0; i < MT; ++i)
        aoff[i] = (((wr * MT + i) * 16 + row16) << 5) + ((quad ^ swz) << 3);
#pragma unroll
    for (int j = 0; j < NT; ++j)
        boff[j] = (((wc * NT + j) * 16 + row16) << 5) + ((quad ^ swz) << 3);

    const int nkb = K >> 5;
    for (int kb = 0; kb < nkb; ++kb) {
        __syncthreads();
        {
            const size_t ka = (size_t)kb * Mb + mb0;
#pragma unroll
            for (int c = w; c < BMt / 16; c += 4) {
                gl_lds16(Ah + ((ka + c) << 9) + lane * 8, &lsAh[c << 9]);
                gl_lds16(Al + ((ka + c) << 9) + lane * 8, &lsAl[c << 9]);
            }
            const size_t kB = (size_t)kb * Nb + nb0;
#pragma unroll
            for (int c = w; c < BNt / 16; c += 4) {
                gl_lds16(Bh + ((kB + c) << 9) + lane * 8, &lsBh[c << 9]);
                gl_lds16(Bl + ((kB + c) << 9) + lane * 8, &lsBl[c << 9]);
            }
        }
        __syncthreads();

        s8v ah[MT], al[MT], bh[NT], bl[NT];
#pragma unroll
        for (int i = 0; i < MT; ++i) {
            ah[i] = *(const s8v*)&lsAh[aoff[i]];
            al[i] = *(const s8v*)&lsAl[aoff[i]];
        }
#pragma unroll
        for (int j = 0; j < NT; ++j) {
            bh[j] = *(const s8v*)&lsBh[boff[j]];
            bl[j] = *(const s8v*)&lsBl[boff[j]];
        }
#pragma unroll
        for (int i = 0; i < MT; ++i)
#pragma unroll
            for (int j = 0; j < NT; ++j) {
                acc[i][j] = __builtin_amdgcn_mfma_f32_16x16x32_bf16(
                    al[i], bh[j], acc[i][j], 0, 0, 0);
                acc[i][j] = __builtin_amdgcn_mfma_f32_16x16x32_bf16(
                    ah[i], bl[j], acc[i][j], 0, 0, 0);
                acc[i][j] = __builtin_amdgcn_mfma_f32_16x16x32_bf16(
                    ah[i], bh[j], acc[i][j], 0, 0, 0);
            }
    }

#pragma unroll
    for (int j = 0; j < NT; ++j) {
        const int col = bn * BNt + (wc * NT + j) * 16 + row16;
        const float bc = bias[col];
#pragma unroll
        for (int i = 0; i < MT; ++i) {
            const int row0 = bm * BMt + (wr * MT + i) * 16 + quad * 4;
#pragma unroll
            for (int r = 0; r < 4; ++r)
                C[(size_t)(row0 + r) * N + col] = acc[i][j][r] + bc;
        }
    }
}

// ---------------------------------------------------------------------------
// Depthwise causal conv (k=4) + bias + SiLU.  xconv[bt, d]
// ---------------------------------------------------------------------------
__global__ __launch_bounds__(256) void conv_silu_kernel(
    const float* __restrict__ xz, const float* __restrict__ cw,
    const float* __restrict__ cb, float* __restrict__ out)
{
    const int idx = blockIdx.x * 256 + threadIdx.x;
    const int d = idx % D_INNER;
    const int bt = idx / D_INNER;
    const int t = bt & (SEQ - 1);

    const float w0 = cw[d * 4 + 0];
    const float w1 = cw[d * 4 + 1];
    const float w2 = cw[d * 4 + 2];
    const float w3 = cw[d * 4 + 3];

    float acc = cb[d];
    const size_t base = (size_t)bt * NXZ + d;
    if (t >= 3) acc = fmaf(xz[base - 3 * (size_t)NXZ], w0, acc);
    if (t >= 2) acc = fmaf(xz[base - 2 * (size_t)NXZ], w1, acc);
    if (t >= 1) acc = fmaf(xz[base - 1 * (size_t)NXZ], w2, acc);
    acc = fmaf(xz[base], w3, acc);

    out[idx] = acc / (1.f + __expf(-acc));
}

// ---------------------------------------------------------------------------
// x-proj: x_ssm[row, 0:33] = xconv[row, :] @ xp_W^T + xp_b. One wave per row.
// ---------------------------------------------------------------------------
__global__ __launch_bounds__(64) void xproj_kernel(
    const float* __restrict__ X, const float* __restrict__ W,
    const float* __restrict__ b, float* __restrict__ out)
{
    const int row = blockIdx.x;
    const int lane = threadIdx.x;

    float xr[24];
#pragma unroll
    for (int i = 0; i < 24; ++i)
        xr[i] = X[(size_t)row * D_INNER + lane + i * 64];

    for (int n = 0; n < NSSM; ++n) {
        float acc = 0.f;
        const float* wrow = W + (size_t)n * D_INNER;
#pragma unroll
        for (int i = 0; i < 24; ++i)
            acc = fmaf(xr[i], wrow[lane + i * 64], acc);
        acc += __shfl_xor(acc, 32);
        acc += __shfl_xor(acc, 16);
        acc += __shfl_xor(acc, 8);
        acc += __shfl_xor(acc, 4);
        acc += __shfl_xor(acc, 2);
        acc += __shfl_xor(acc, 1);
        if (lane == 0) out[(size_t)row * NSSM + n] = acc + b[n];
    }
}

// ---------------------------------------------------------------------------
// Chunked selective scan, thread-per-channel layout (16 states in registers).
// Grid: (D_INNER/256, NCH, BATCH); block 256.  Stream index for summaries:
// addr(c,n,b,d) = c*NS + n*BD + b*D_INNER + d  (coalesced in d per n).
// ---------------------------------------------------------------------------
__global__ __launch_bounds__(256) void scan_phase1(
    const float* __restrict__ xssm, const float* __restrict__ xconv,
    const float* __restrict__ dpW, const float* __restrict__ dpb,
    const float* __restrict__ A_log,
    float* __restrict__ Ap, float* __restrict__ Hp)
{
    const int d = blockIdx.x * 256 + threadIdx.x;
    const int c = blockIdx.y;
    const int b = blockIdx.z;

    const float w  = dpW[d];
    const float bb = dpb[d];
    float An[D_STATE];
#pragma unroll
    for (int n = 0; n < D_STATE; ++n)
        An[n] = -__expf(A_log[d * D_STATE + n]);

    const int bt0 = b * SEQ + c * LCH;

    float h[D_STATE], ap[D_STATE];
#pragma unroll
    for (int n = 0; n < D_STATE; ++n) { h[n] = 0.f; ap[n] = 1.f; }

    float xv = xconv[(size_t)bt0 * D_INNER + d];
    for (int t = 0; t < LCH; ++t) {
        const int tn = (t + 1 < LCH) ? (t + 1) : t;
        const float xv_nxt = xconv[(size_t)(bt0 + tn) * D_INNER + d];

        const float* row = xssm + (size_t)(bt0 + t) * NSSM;  // wave-uniform
        const float dr = row[32];
        const float u = fmaf(dr, w, bb);
        const float delta = __logf(1.f + __expf(u));
        const float dx = delta * xv;
#pragma unroll
        for (int n = 0; n < D_STATE; ++n) {
            const float dA = __expf(delta * An[n]);
            h[n] = fmaf(dA, h[n], dx * row[n]);
            ap[n] *= dA;
        }
        xv = xv_nxt;
    }

    const size_t bd = (size_t)b * D_INNER + d;
#pragma unroll
    for (int n = 0; n < D_STATE; ++n) {
        Ap[(size_t)c * NS + (size_t)n * BD + bd] = ap[n];
        Hp[(size_t)c * NS + (size_t)n * BD + bd] = h[n];
    }
}

// Phase 2: serial prefix over chunk summaries; writes h-at-chunk-start
// IN PLACE into Ap (read-before-write per thread, safe).
__global__ __launch_bounds__(256) void scan_phase2(
    float* __restrict__ Ap, const float* __restrict__ Hp)
{
    const size_t s = (size_t)blockIdx.x * 256 + threadIdx.x;
    float carry = 0.f;
#pragma unroll 4
    for (int c = 0; c < NCH; ++c) {
        const float a  = Ap[(size_t)c * NS + s];
        const float hp = Hp[(size_t)c * NS + s];
        Ap[(size_t)c * NS + s] = carry;
        carry = fmaf(a, carry, hp);
    }
}

// Phase 3: replay with correct h_start; emit (y + x*D)*silu(z) into xconv.
__global__ __launch_bounds__(256) void scan_phase3(
    const float* __restrict__ xssm, float* __restrict__ xconv,
    const float* __restrict__ xz,
    const float* __restrict__ dpW, const float* __restrict__ dpb,
    const float* __restrict__ A_log, const float* __restrict__ Dvec,
    const float* __restrict__ Hs)
{
    const int d = blockIdx.x * 256 + threadIdx.x;
    const int c = blockIdx.y;
    const int b = blockIdx.z;

    const float w  = dpW[d];
    const float bb = dpb[d];
    const float Dd = Dvec[d];
    float An[D_STATE];
#pragma unroll
    for (int n = 0; n < D_STATE; ++n)
        An[n] = -__expf(A_log[d * D_STATE + n]);

    const int bt0 = b * SEQ + c * LCH;
    const size_t bd = (size_t)b * D_INNER + d;

    float h[D_STATE];
#pragma unroll
    for (int n = 0; n < D_STATE; ++n)
        h[n] = Hs[(size_t)c * NS + (size_t)n * BD + bd];

    float xv = xconv[(size_t)bt0 * D_INNER + d];
    float zv = xz[(size_t)bt0 * NXZ + D_INNER + d];
    for (int t = 0; t < LCH; ++t) {
        const int tn = (t + 1 < LCH) ? (t + 1) : t;
        const float xv_nxt = xconv[(size_t)(bt0 + tn) * D_INNER + d];
        const float zv_nxt = xz[(size_t)(bt0 + tn) * NXZ + D_INNER + d];

        const float* row = xssm + (size_t)(bt0 + t) * NSSM;  // wave-uniform
        const float dr = row[32];
        const float u = fmaf(dr, w, bb);
        const float delta = __logf(1.f + __expf(u));
        const float dx = delta * xv;

        float y = 0.f;
#pragma unroll
        for (int n = 0; n < D_STATE; ++n) {
            const float dA = __expf(delta * An[n]);
            h[n] = fmaf(dA, h[n], dx * row[n]);
            y = fmaf(row[16 + n], h[n], y);
        }
        y = fmaf(xv, Dd, y);
        const float sg = zv / (1.f + __expf(-zv));
        xconv[(size_t)(bt0 + t) * D_INNER + d] = y * sg;

        xv = xv_nxt; zv = zv_nxt;
    }
}

// ---------------------------------------------------------------------------
extern "C" void kernel_launch(void* const* d_in, const int* in_sizes, int n_in,
                              void* d_out, int out_size, void* d_ws, size_t ws_size,
                              hipStream_t stream)
{
    const float* x      = (const float*)d_in[0];
    const float* in_W   = (const float*)d_in[1];
    const float* in_b   = (const float*)d_in[2];
    const float* conv_W = (const float*)d_in[3];
    const float* conv_b = (const float*)d_in[4];
    const float* xp_W   = (const float*)d_in[5];
    const float* xp_b   = (const float*)d_in[6];
    const float* dp_W   = (const float*)d_in[7];
    const float* dp_b   = (const float*)d_in[8];
    const float* A_log  = (const float*)d_in[9];
    const float* Dvec   = (const float*)d_in[10];
    const float* out_W  = (const float*)d_in[11];
    const float* out_b  = (const float*)d_in[12];
    float* out = (float*)d_out;

    // workspace layout (float units)
    float* ws    = (float*)d_ws;
    float* xz    = ws;                                       // 12,582,912
    float* xconv = xz + (size_t)MROWS * NXZ;                 //  6,291,456
    float* xssm  = xconv + (size_t)MROWS * D_INNER;          //    135,168
    float* Hp    = xssm + (size_t)MROWS * NSSM;              //  3,145,728
    unsigned short* inWh  = (unsigned short*)(Hp + (size_t)NCH * NS);
    unsigned short* inWl  = inWh + (size_t)NXZ * D_MODEL;
    unsigned short* outWh = inWl + (size_t)NXZ * D_MODEL;
    unsigned short* outWl = outWh + (size_t)D_MODEL * D_INNER;

    // Ap (12.58 MB) lives in d_out: dead scratch after gemm1 consumes xh/xl,
    // until the final GEMM writes the real output. Exact size fit.
    float* Ap = (float*)d_out;                               // NCH*NS floats

    // x-split lives in d_out too (consumed by gemm1 before Ap is written)
    unsigned short* xh = (unsigned short*)d_out;
    unsigned short* xl = xh + (size_t)MROWS * D_MODEL;
    // xcg-split aliases the (dead-after-phase3) xz region
    unsigned short* xcgh = (unsigned short*)xz;
    unsigned short* xcgl = xcgh + (size_t)MROWS * D_INNER;

    // 0) split+retile x, in_W, out_W
    split_retile<<<(MROWS * D_MODEL) / 256, 256, 0, stream>>>(x, xh, xl, MROWS, D_MODEL);
    split_retile<<<(NXZ * D_MODEL) / 256, 256, 0, stream>>>(in_W, inWh, inWl, NXZ, D_MODEL);
    split_retile<<<(D_MODEL * D_INNER) / 256, 256, 0, stream>>>(out_W, outWh, outWl, D_MODEL, D_INNER);

    // 1) in-proj: xz = x @ in_W^T + in_b   (M=4096, N=3072, K=768)
    {
        dim3 grid(NXZ / 128, MROWS / 128);
        gemm_split<128, 128><<<grid, 256, 0, stream>>>(
            xh, xl, inWh, inWl, in_b, xz, MROWS, NXZ, D_MODEL);
    }
    // 2) depthwise conv + SiLU
    conv_silu_kernel<<<(MROWS * D_INNER) / 256, 256, 0, stream>>>(xz, conv_W, conv_b, xconv);
    // 3) x-proj
    xproj_kernel<<<MROWS, 64, 0, stream>>>(xconv, xp_W, xp_b, xssm);
    // 4) chunked selective scan (thread-per-channel, registers for 16 states)
    {
        dim3 grid13(D_INNER / 256, NCH, BATCH);
        scan_phase1<<<grid13, 256, 0, stream>>>(xssm, xconv, dp_W, dp_b, A_log, Ap, Hp);
        scan_phase2<<<NS / 256, 256, 0, stream>>>(Ap, Hp);
        scan_phase3<<<grid13, 256, 0, stream>>>(xssm, xconv, xz, dp_W, dp_b, A_log,
                                                Dvec, Ap);
    }
    // 5) split+retile gated output (xz region is dead now)
    split_retile<<<(MROWS * D_INNER) / 256, 256, 0, stream>>>(xconv, xcgh, xcgl, MROWS, D_INNER);
    // 6) out-proj: out = y @ out_W^T + out_b  (M=4096, N=768, K=1536)
    {
        dim3 grid(D_MODEL / 64, MROWS / 64);
        gemm_split<64, 64><<<grid, 256, 0, stream>>>(
            xcgh, xcgl, outWh, outWl, out_b, out, MROWS, D_MODEL, D_INNER);
    }
}